// Round 17
// baseline (413.703 us; speedup 1.0000x reference)
//
#include <hip/hip_runtime.h>
#include <hip/hip_bf16.h>
#include <math.h>

typedef unsigned short u16;
typedef __attribute__((ext_vector_type(8))) __bf16 bf16x8;
typedef __attribute__((ext_vector_type(4))) float f32x4;
typedef __attribute__((ext_vector_type(16))) float f32x16;
typedef __attribute__((ext_vector_type(8))) u16 u16x8;
typedef __attribute__((ext_vector_type(4))) u16 u16x4;
typedef __attribute__((ext_vector_type(4))) unsigned u32x4;

#define T_SEQ 2048
#define DMODEL 2048
#define NH 16
#define DHEAD 128
#define BATCH 4
#define QK_STR 4096             // Cqk row stride (Q | K)
#define ATTN_SCALE 0.08838834764831845f
#define QSCALE_LOG2E 0.1275411278534803f   // ATTN_SCALE * log2(e)
#define ROPE_EXP_C  -0.20762050593045857f  // -log2(10000)/64

#define GLOAD(gp, lp) __builtin_amdgcn_global_load_lds( \
    (const __attribute__((address_space(1))) void*)(gp), \
    (__attribute__((address_space(3))) void*)(lp), 16, 0, 0)

#define BAR() __builtin_amdgcn_s_barrier()
#define VMCNT4() asm volatile("s_waitcnt vmcnt(4)" ::: "memory")
#define MFMA32(A, B, C) __builtin_amdgcn_mfma_f32_32x32x16_bf16(A, B, C, 0, 0, 0)

__device__ __forceinline__ float b2f(u16 u) {
  union { float f; unsigned int i; } x; x.i = ((unsigned int)u) << 16; return x.f;
}
__device__ __forceinline__ u16 f2b(float f) {
  __bf16 h = (__bf16)f;
  return *(u16*)&h;
}
__device__ __forceinline__ unsigned pk2(float lo, float hi2) {
  __bf16 a = (__bf16)lo, b = (__bf16)hi2;
  unsigned short ua = *(unsigned short*)&a, ub = *(unsigned short*)&b;
  return (unsigned)ua | ((unsigned)ub << 16);
}

// ---------------- cast x: f32 -> bf16 ----------------
__global__ __launch_bounds__(256) void cast_f32_bf16(const float* __restrict__ in,
                                                     u16* __restrict__ out) {
  long i = ((long)blockIdx.x * 256 + threadIdx.x) * 8;
  float4 a = *(const float4*)(in + i);
  float4 b = *(const float4*)(in + i + 4);
  u16x8 r;
  r[0] = f2b(a.x); r[1] = f2b(a.y); r[2] = f2b(a.z); r[3] = f2b(a.w);
  r[4] = f2b(b.x); r[5] = f2b(b.y); r[6] = f2b(b.z); r[7] = f2b(b.w);
  *(u16x8*)(out + i) = r;
}

// ---------------- all 4 weight transposes in one launch: W[k][n] f32 -> Wt[n][k] bf16 ----------------
__global__ __launch_bounds__(256) void wtrans4_kernel(const float* __restrict__ W0,
                                                      const float* __restrict__ W1,
                                                      const float* __restrict__ W2,
                                                      const float* __restrict__ W3,
                                                      u16* __restrict__ WtBase) {
  __shared__ float tile[64][65];
  const int z = blockIdx.z;
  const float* W = (z == 0) ? W0 : (z == 1) ? W1 : (z == 2) ? W2 : W3;
  u16* Wt = WtBase + (long)z * 4194304;   // 2048*2048 elements per weight
  const int k0 = blockIdx.x * 64, n0 = blockIdx.y * 64;
  const int c = threadIdx.x & 63, r4 = threadIdx.x >> 6;
#pragma unroll
  for (int p = 0; p < 16; p++) {
    int r = p * 4 + r4;
    tile[r][c] = W[(long)(k0 + r) * DMODEL + n0 + c];
  }
  __syncthreads();
#pragma unroll
  for (int p = 0; p < 16; p++) {
    int r = p * 4 + r4;
    Wt[(long)(n0 + r) * DMODEL + k0 + c] = f2b(tile[c][r]);
  }
}

// ---------------- standalone RoPE on the K region only (Cqk cols 2048..4095) ----------------
__global__ __launch_bounds__(256) void rope_k_kernel(u16* __restrict__ X) {
  int idx = blockIdx.x * 256 + threadIdx.x;  // B*T*256 threads, 8 elems each
  int c8 = idx & 255;                        // chunk of 8 within the 2048 K cols
  long row = idx >> 8;
  int t = (int)(row & (T_SEQ - 1));
  int i4 = c8 & 15;                          // chunk within the 128-wide head
  long off = row * QK_STR + 2048 + (long)c8 * 8;
  u16x8 v = *(u16x8*)(X + off);
  float o[8];
#pragma unroll
  for (int j = 0; j < 4; j++) {
    int i = i4 * 4 + j;                      // pair index 0..63
    float inv = __builtin_amdgcn_exp2f((float)i * ROPE_EXP_C);
    float ang = (float)t * inv;
    float cs = __cosf(ang), sn = __sinf(ang);
    float x0 = b2f(v[2 * j]), x1 = b2f(v[2 * j + 1]);
    o[2 * j]     = x0 * cs - x1 * sn;
    o[2 * j + 1] = x1 * cs + x0 * sn;
  }
  u16x8 r;
#pragma unroll
  for (int j = 0; j < 8; j++) r[j] = f2b(o[j]);
  *(u16x8*)(X + off) = r;
}

// ---------------- GEMM: C[M][N] = A[M][K] * Bt[N][K]^T (bf16 in, f32 acc) ----------------
// 256x256 8-phase template, BK=64, 512 thr = 8 waves (2M x 4N), per-wave 128x64 out.
// VWRITE=1 (QKV): V-column blocks (col0>=4096) write plain-layout Vt directly via
// per-wave LDS scratch transpose (measured FREE vs strided C-writes, r16).
#define LOAD_A(q)                                                      \
  _Pragma("unroll") for (int k = 0; k < 2; k++)                        \
  _Pragma("unroll") for (int m = 0; m < 2; m++) {                      \
    int r = wr * 128 + (q) * 32 + m * 16 + lr;                         \
    int cc = (k * 4 + lc) ^ (r & 7);                                   \
    a[k][m] = *(const bf16x8*)&sAb[par * 16384 + r * 64 + cc * 8];     \
  }

#define LOAD_B()                                                       \
  _Pragma("unroll") for (int k = 0; k < 2; k++)                        \
  _Pragma("unroll") for (int n = 0; n < 4; n++) {                      \
    int r = wc * 64 + n * 16 + lr;                                     \
    int cc = (k * 4 + lc) ^ (r & 7);                                   \
    b[k][n] = *(const bf16x8*)&sBb[par * 16384 + r * 64 + cc * 8];     \
  }

#define MFMA_QUAD(q)                                                   \
  _Pragma("unroll") for (int k = 0; k < 2; k++)                        \
  _Pragma("unroll") for (int n = 0; n < 4; n++)                        \
  _Pragma("unroll") for (int m = 0; m < 2; m++)                        \
    acc[(q) * 2 + m][n] = __builtin_amdgcn_mfma_f32_16x16x32_bf16(     \
        a[k][m], b[k][n], acc[(q) * 2 + m][n], 0, 0, 0);

#define STAGE_HALF(g, ld, ldsp, rc0, t_, h_)                           \
  _Pragma("unroll") for (int j = 0; j < 2; j++) {                      \
    int rl = (h_) * 128 + wid * 16 + j * 8 + (lane >> 3);              \
    int cc = (lane & 7) ^ (lane >> 3);                                 \
    GLOAD((g) + ((rc0) + rl) * (long)(ld) + (long)(t_) * 64 + cc * 8,  \
          (ldsp) + (h_) * 128 * 64 + (wid * 16 + j * 8) * 64);         \
  }

template <int OUT_F32, int VWRITE>
__global__ __launch_bounds__(512, 2) void gemm_bt(const u16* __restrict__ A, long lda,
                                                  const u16* __restrict__ Bt,
                                                  void* __restrict__ Cv, long ldc,
                                                  u16* __restrict__ VtOut,
                                                  int M, int N, int K) {
  __shared__ u16 smem[65536];               // sA dbuf (32K u16) | sB dbuf (32K u16)
  u16* sAb = smem;
  u16* sBb = smem + 32768;
  const int tid = threadIdx.x, lane = tid & 63, wid = tid >> 6;
  const int wr = wid >> 2, wc = wid & 3;
  const int lr = lane & 15, lc = lane >> 4;
  const int id = blockIdx.x;
  const int per = (N >> 8) >> 3;             // col-tiles per XCD (1 for N=2048, 3 for 6144)
  const int g8 = id >> 3;
  const long col0 = (long)((id & 7) + 8 * (g8 % per)) * 256;
  const long row0 = (long)(g8 / per) * 256;
  const int NT = K >> 6;                     // NT must be even (K%128==0) for unroll 2

  f32x4 acc[8][4] = {};
  bf16x8 a[2][2], b[2][4];

  STAGE_HALF(Bt, K, sBb, col0, 0, 0);
  STAGE_HALF(Bt, K, sBb, col0, 0, 1);
  STAGE_HALF(A, lda, sAb, row0, 0, 0);
  STAGE_HALF(A, lda, sAb, row0, 0, 1);
  STAGE_HALF(Bt, K, sBb + 16384, col0, 1, 0);
  STAGE_HALF(Bt, K, sBb + 16384, col0, 1, 1);
  VMCNT4();
  BAR();

#pragma unroll 2
  for (int t = 0; t < NT; t++) {
    const int par = t & 1;
    // ---- phase 0 ----
    LOAD_B();
    LOAD_A(0);
    if (t + 1 < NT) { STAGE_HALF(A, lda, sAb + (par ^ 1) * 16384, row0, t + 1, 0); }
    BAR();
    __builtin_amdgcn_s_setprio(1); MFMA_QUAD(0); __builtin_amdgcn_s_setprio(0);
    BAR();
    // ---- phase 1 ----
    LOAD_A(1);
    if (t + 1 < NT) { STAGE_HALF(A, lda, sAb + (par ^ 1) * 16384, row0, t + 1, 1); }
    if (t + 2 < NT) { STAGE_HALF(Bt, K, sBb + par * 16384, col0, t + 2, 0); }
    BAR();
    __builtin_amdgcn_s_setprio(1); MFMA_QUAD(1); __builtin_amdgcn_s_setprio(0);
    BAR();
    // ---- phase 2 ----
    LOAD_A(2);
    if (t + 2 < NT) { STAGE_HALF(Bt, K, sBb + par * 16384, col0, t + 2, 1); }
    BAR();
    __builtin_amdgcn_s_setprio(1); MFMA_QUAD(2); __builtin_amdgcn_s_setprio(0);
    BAR();
    // ---- phase 3 ----
    LOAD_A(3);
    VMCNT4();
    BAR();
    __builtin_amdgcn_s_setprio(1); MFMA_QUAD(3); __builtin_amdgcn_s_setprio(0);
    BAR();
  }

  if (VWRITE && col0 >= 4096) {
    // transpose 128x64 wave-tile through private LDS scratch; store plain Vt rows.
    u16* scr = smem + wid * 8192;            // 16KB per wave, whole 128KB used
#pragma unroll
    for (int mf = 0; mf < 8; mf++)
#pragma unroll
      for (int n = 0; n < 4; n++)
#pragma unroll
        for (int i = 0; i < 4; i++) {
          int sl = mf * 16 + lc * 4 + i;     // s-local 0..127
          int fr = n * 16 + lr;              // f-local 0..63
          scr[fr * 128 + (((sl >> 3) ^ (fr & 7)) << 3) + (sl & 7)] = f2b(acc[mf][n][i]);
        }
    asm volatile("s_waitcnt lgkmcnt(0)" ::: "memory");  // wave-local: own writes done
    const int h0 = (int)((col0 - 4096) >> 7) + (wc >> 1);
    const int f00 = (wc & 1) * 64;
    const long rowbase = row0 + wr * 128;
    const int bb = (int)(rowbase >> 11);
    const int s0 = (int)(rowbase & 2047);
#pragma unroll
    for (int c = 0; c < 16; c++) {
      int fr = c * 4 + (lane >> 4);
      int pc = (lane & 15) ^ (fr & 7);
      u16x8 vv = *(u16x8*)&scr[fr * 128 + pc * 8];
      *(u16x8*)(VtOut + ((long)((bb * 16 + h0) * 128 + f00 + fr)) * 2048 +
                s0 + (lane & 15) * 8) = vv;
    }
  } else {
#pragma unroll
    for (int mf = 0; mf < 8; mf++)
#pragma unroll
      for (int n = 0; n < 4; n++)
#pragma unroll
        for (int i = 0; i < 4; i++) {
          long row = row0 + wr * 128 + mf * 16 + lc * 4 + i;
          long col = col0 + wc * 64 + n * 16 + lr;
          float v = acc[mf][n][i];
          if (OUT_F32) ((float*)Cv)[row * ldc + col] = v;
          else ((u16*)Cv)[row * ldc + col] = f2b(v);
        }
  }
}

// ---------------- flash attention: swapped QK^T, 32x32 MFMA, P in-register ----------------
// QBLK=256: 512 thr = 8 waves, each wave owns 32 q-rows (per-wave code identical to
// the proven r11/r12 schedule). K/V tiles now serve 256 q-rows -> fetch halves; LDS
// still 64KB -> 2 blocks/CU but 16 waves/CU = 4 waves/SIMD (2x TLP, was 2/SIMD).
__global__ __launch_bounds__(512, 2) void attn_kernel(const u16* __restrict__ QK,
                                                      const u16* __restrict__ Vt,
                                                      u16* __restrict__ Y) {
  __shared__ u16 lK[2][64 * 128];   // K tile: 64 s-rows x 128 d (chunk-swizzled)
  __shared__ u16 lV[2][128 * 64];   // Vt tile: 128 d-rows x 64 s (chunk-swizzled)
  const int tid = threadIdx.x, lane = tid & 63, w = tid >> 6;   // w in 0..7
  const int hi = lane >> 5, l31 = lane & 31;
  const int id = blockIdx.x;
  const int qt = 7 - (id >> 6);     // 8 q-tiles of 256 rows; longest first
  const int bh = id & 63;
  const int b = bh >> 4, h = bh & 15;
  const int qg = qt * 256 + w * 32 + l31;   // this lane's q row (global)
  const int swz = l31 & 7;

  // Q fragments (B-operand): qf[kd][j] = rope(Q[qg])[kd*16 + hi*8 + j] * scale
  bf16x8 qf[8];
  const long qrow = (long)(b * T_SEQ + qg) * QK_STR + h * DHEAD;
#pragma unroll
  for (int kd = 0; kd < 8; kd++) {
    u16x8 raw = *(const u16x8*)(QK + qrow + kd * 16 + hi * 8);
    bf16x8 q;
#pragma unroll
    for (int jj = 0; jj < 4; jj++) {
      int pi = kd * 8 + hi * 4 + jj;          // pair index 0..63
      float ang = (float)qg * __builtin_amdgcn_exp2f((float)pi * ROPE_EXP_C);
      float cs = __cosf(ang), sn = __sinf(ang);
      float x0 = b2f(raw[2 * jj]), x1 = b2f(raw[2 * jj + 1]);
      q[2 * jj]     = (__bf16)((x0 * cs - x1 * sn) * QSCALE_LOG2E);
      q[2 * jj + 1] = (__bf16)((x1 * cs + x0 * sn) * QSCALE_LOG2E);
    }
    qf[kd] = q;
  }

  f32x16 o0 = {}, o1 = {}, o2 = {}, o3 = {};  // O^T[d][q]: q lane-local
  float m_st = -INFINITY, l_st = 0.f;
  const int nt = (qt + 1) * 4;

// 8 waves: each wave covers slot-groups (w*2+j)*64, j=0..1 -> 2 GLOADs per array
#define STAGE(nb, kt_)                                                              \
  {                                                                                 \
    _Pragma("unroll")                                                               \
    for (int j = 0; j < 2; j++) {                                                   \
      int sb = (w * 2 + j) * 64;                                                    \
      int slot = sb + lane;                                                         \
      { int r = slot >> 4, pc = slot & 15, cc = pc ^ (r & 7);                       \
        GLOAD(QK + (long)(b * T_SEQ + (kt_) * 64 + r) * QK_STR + 2048 +             \
                  h * DHEAD + cc * 8,                                               \
              &lK[nb][sb * 8]); }                                                   \
      { int r = slot >> 3, pc = slot & 7, cc = pc ^ (r & 7);                        \
        GLOAD(Vt + (long)(bh * DHEAD + r) * T_SEQ + (kt_) * 64 + cc * 8,            \
              &lV[nb][sb * 8]); }                                                   \
    }                                                                               \
  }

  STAGE(0, 0);
  __syncthreads();

  for (int kt = 0; kt < nt; kt++) {
    const int cur = kt & 1;
    if (kt + 1 < nt) STAGE(cur ^ 1, kt + 1);

    // S^T = mfma(K, Q): st0 = s 0..31, st1 = s 32..63; lane: q=l31, s=crow(r,hi)
    f32x16 st0 = {}, st1 = {};
    __builtin_amdgcn_s_setprio(1);
#pragma unroll
    for (int kd = 0; kd < 8; kd++) {
      int pc = (kd * 2 + hi) ^ swz;
      bf16x8 kf0 = *(const bf16x8*)&lK[cur][l31 * 128 + pc * 8];
      bf16x8 kf1 = *(const bf16x8*)&lK[cur][(32 + l31) * 128 + pc * 8];
      st0 = MFMA32(kf0, qf[kd], st0);
      st1 = MFMA32(kf1, qf[kd], st1);
    }
    __builtin_amdgcn_s_setprio(0);

    // causal mask (diagonal region only)
    if (kt * 64 + 63 > qt * 256 + w * 32) {
#pragma unroll
      for (int r = 0; r < 16; r++) {
        int sl = kt * 64 + (r & 3) + 8 * (r >> 2) + 4 * hi;
        if (sl > qg) st0[r] = -1e30f;
        if (sl + 32 > qg) st1[r] = -1e30f;
      }
    }

    // online softmax, exp2 domain, in-lane + one cross-half shfl reduce
    float mx = -1e30f;
#pragma unroll
    for (int r = 0; r < 16; r++) mx = fmaxf(mx, fmaxf(st0[r], st1[r]));
    mx = fmaxf(mx, __shfl_xor(mx, 32, 64));
    if (__any(mx > m_st + 8.0f)) {     // defer-max
      float mnew = fmaxf(m_st, mx);
      float corr = __builtin_amdgcn_exp2f(m_st - mnew);
      m_st = mnew;
      l_st *= corr;
#pragma unroll
      for (int r = 0; r < 16; r++) {
        o0[r] *= corr; o1[r] *= corr; o2[r] *= corr; o3[r] *= corr;
      }
    }
    float rs = 0.f;
#pragma unroll
    for (int r = 0; r < 16; r++) {
      st0[r] = __builtin_amdgcn_exp2f(st0[r] - m_st); rs += st0[r];
      st1[r] = __builtin_amdgcn_exp2f(st1[r] - m_st); rs += st1[r];
    }
    l_st += rs + __shfl_xor(rs, 32, 64);

    // P -> bf16 PV B-frags: 2 shfls/group (send hi?A:B); O^T += mfma(Vt, P)
    __builtin_amdgcn_s_setprio(1);
#define PVHALF(stX, sb)                                                        \
    _Pragma("unroll")                                                          \
    for (int g = 0; g < 2; g++) {                                              \
      unsigned A0 = pk2(stX[8 * g + 0], stX[8 * g + 1]);                       \
      unsigned A1 = pk2(stX[8 * g + 2], stX[8 * g + 3]);                       \
      unsigned B0 = pk2(stX[8 * g + 4], stX[8 * g + 5]);                       \
      unsigned B1 = pk2(stX[8 * g + 6], stX[8 * g + 7]);                       \
      unsigned r0 = __shfl_xor(hi ? A0 : B0, 32, 64);                          \
      unsigned r1 = __shfl_xor(hi ? A1 : B1, 32, 64);                          \
      u32x4 pw;                                                                \
      pw[0] = hi ? r0 : A0;                                                    \
      pw[1] = hi ? r1 : A1;                                                    \
      pw[2] = hi ? B0 : r0;                                                    \
      pw[3] = hi ? B1 : r1;                                                    \
      bf16x8 pa = *(bf16x8*)&pw;                                               \
      const int ks = (sb) * 2 + g;                                             \
      int pc0 = (ks * 2 + hi) ^ swz;                                           \
      bf16x8 vb0 = *(const bf16x8*)&lV[cur][(l31) * 64 + pc0 * 8];             \
      o0 = MFMA32(vb0, pa, o0);                                                \
      bf16x8 vb1 = *(const bf16x8*)&lV[cur][(32 + l31) * 64 + pc0 * 8];        \
      o1 = MFMA32(vb1, pa, o1);                                                \
      bf16x8 vb2 = *(const bf16x8*)&lV[cur][(64 + l31) * 64 + pc0 * 8];        \
      o2 = MFMA32(vb2, pa, o2);                                                \
      bf16x8 vb3 = *(const bf16x8*)&lV[cur][(96 + l31) * 64 + pc0 * 8];        \
      o3 = MFMA32(vb3, pa, o3);                                                \
    }
    PVHALF(st0, 0)
    PVHALF(st1, 1)
#undef PVHALF
    __builtin_amdgcn_s_setprio(0);

    __syncthreads();
  }

  // epilogue: O^T *= 1/l, packed 8B stores into Y [8192][2048]
  float inv = __builtin_amdgcn_rcpf(l_st);
  const long yrow = (long)(b * T_SEQ + qg) * 2048 + h * DHEAD;
#define WR(oN, n)                                                              \
  _Pragma("unroll")                                                            \
  for (int rq = 0; rq < 4; rq++) {                                             \
    u16x4 pk;                                                                  \
    _Pragma("unroll")                                                          \
    for (int j = 0; j < 4; j++) pk[j] = f2b(oN[rq * 4 + j] * inv);             \
    *(u16x4*)(Y + yrow + (n) * 32 + rq * 8 + hi * 4) = pk;                     \
  }
  WR(o0, 0) WR(o1, 1) WR(o2, 2) WR(o3, 3)
#undef WR
#undef STAGE
}

extern "C" void kernel_launch(void* const* d_in, const int* in_sizes, int n_in,
                              void* d_out, int out_size, void* d_ws, size_t ws_size,
                              hipStream_t stream) {
  const float* x  = (const float*)d_in[0];
  const float* Wq = (const float*)d_in[1];
  const float* Wk = (const float*)d_in[2];
  const float* Wv = (const float*)d_in[3];
  const float* Wo = (const float*)d_in[4];
  float* out = (float*)d_out;
  char* ws = (char*)d_ws;

  const long MB = 1048576L;
  // layout (160MB total): xb 0-32MB (input bf16; becomes Y after attn);
  // Wt4 32-64MB (Wqt|Wkt|Wvt|Wot); Cqk 64-128MB ([8192][4096]: Q-raw | K-roped);
  // Vt 128-160MB ([64*128][2048] plain).
  u16* xb  = (u16*)(ws);
  u16* Wt4 = (u16*)(ws + 32 * MB);
  u16* Cqk = (u16*)(ws + 64 * MB);
  u16* Vtb = (u16*)(ws + 128 * MB);
  u16* Yb  = xb;    // alias: xb dead after QKV projection

  cast_f32_bf16<<<8192, 256, 0, stream>>>(x, xb);
  dim3 wt_g(32, 32, 4);
  wtrans4_kernel<<<wt_g, 256, 0, stream>>>(Wq, Wk, Wv, Wo, Wt4);

  // fused QKV projection: QK cols -> Cqk (ldc 4096); V cols -> Vt directly (transposed)
  gemm_bt<0, 1><<<768, 512, 0, stream>>>(xb, 2048, Wt4, Cqk, 4096, Vtb,
                                         8192, 6144, 2048);

  // standalone K-rope (memory-bound, ~10us); Q roped in attn at load
  rope_k_kernel<<<8192, 256, 0, stream>>>(Cqk);

  attn_kernel<<<512, 512, 0, stream>>>(Cqk, Vtb, Yb);

  // output projection: A = Y (contiguous stride 2048); Wot at Wt4 + 3*4M elems
  gemm_bt<1, 0><<<256, 512, 0, stream>>>(Yb, 2048, Wt4 + 3 * 4194304L,
                                         (void*)out, 2048, nullptr,
                                         8192, 2048, 2048);
}

// Round 18
// 413.158 us; speedup vs baseline: 1.0013x; 1.0013x over previous
//
#include <hip/hip_runtime.h>
#include <hip/hip_bf16.h>
#include <math.h>

typedef unsigned short u16;
typedef __attribute__((ext_vector_type(8))) __bf16 bf16x8;
typedef __attribute__((ext_vector_type(4))) float f32x4;
typedef __attribute__((ext_vector_type(16))) float f32x16;
typedef __attribute__((ext_vector_type(8))) u16 u16x8;
typedef __attribute__((ext_vector_type(4))) u16 u16x4;
typedef __attribute__((ext_vector_type(4))) unsigned u32x4;

#define T_SEQ 2048
#define DMODEL 2048
#define NH 16
#define DHEAD 128
#define BATCH 4
#define QK_STR 4096             // Cqk row stride (Q | K)
#define ATTN_SCALE 0.08838834764831845f
#define QSCALE_LOG2E 0.1275411278534803f   // ATTN_SCALE * log2(e)
#define ROPE_EXP_C  -0.20762050593045857f  // -log2(10000)/64

#define GLOAD(gp, lp) __builtin_amdgcn_global_load_lds( \
    (const __attribute__((address_space(1))) void*)(gp), \
    (__attribute__((address_space(3))) void*)(lp), 16, 0, 0)

#define BAR() __builtin_amdgcn_s_barrier()
#define VMCNT4() asm volatile("s_waitcnt vmcnt(4)" ::: "memory")
#define MFMA32(A, B, C) __builtin_amdgcn_mfma_f32_32x32x16_bf16(A, B, C, 0, 0, 0)

__device__ __forceinline__ float b2f(u16 u) {
  union { float f; unsigned int i; } x; x.i = ((unsigned int)u) << 16; return x.f;
}
__device__ __forceinline__ u16 f2b(float f) {
  __bf16 h = (__bf16)f;
  return *(u16*)&h;
}
__device__ __forceinline__ unsigned pk2(float lo, float hi2) {
  __bf16 a = (__bf16)lo, b = (__bf16)hi2;
  unsigned short ua = *(unsigned short*)&a, ub = *(unsigned short*)&b;
  return (unsigned)ua | ((unsigned)ub << 16);
}

// ---------------- cast x: f32 -> bf16 ----------------
__global__ __launch_bounds__(256) void cast_f32_bf16(const float* __restrict__ in,
                                                     u16* __restrict__ out) {
  long i = ((long)blockIdx.x * 256 + threadIdx.x) * 8;
  float4 a = *(const float4*)(in + i);
  float4 b = *(const float4*)(in + i + 4);
  u16x8 r;
  r[0] = f2b(a.x); r[1] = f2b(a.y); r[2] = f2b(a.z); r[3] = f2b(a.w);
  r[4] = f2b(b.x); r[5] = f2b(b.y); r[6] = f2b(b.z); r[7] = f2b(b.w);
  *(u16x8*)(out + i) = r;
}

// ---------------- all 4 weight transposes in one launch: W[k][n] f32 -> Wt[n][k] bf16 ----------------
__global__ __launch_bounds__(256) void wtrans4_kernel(const float* __restrict__ W0,
                                                      const float* __restrict__ W1,
                                                      const float* __restrict__ W2,
                                                      const float* __restrict__ W3,
                                                      u16* __restrict__ WtBase) {
  __shared__ float tile[64][65];
  const int z = blockIdx.z;
  const float* W = (z == 0) ? W0 : (z == 1) ? W1 : (z == 2) ? W2 : W3;
  u16* Wt = WtBase + (long)z * 4194304;   // 2048*2048 elements per weight
  const int k0 = blockIdx.x * 64, n0 = blockIdx.y * 64;
  const int c = threadIdx.x & 63, r4 = threadIdx.x >> 6;
#pragma unroll
  for (int p = 0; p < 16; p++) {
    int r = p * 4 + r4;
    tile[r][c] = W[(long)(k0 + r) * DMODEL + n0 + c];
  }
  __syncthreads();
#pragma unroll
  for (int p = 0; p < 16; p++) {
    int r = p * 4 + r4;
    Wt[(long)(n0 + r) * DMODEL + k0 + c] = f2b(tile[c][r]);
  }
}

// ---------------- standalone RoPE on the K region only (Cqk cols 2048..4095) ----------------
__global__ __launch_bounds__(256) void rope_k_kernel(u16* __restrict__ X) {
  int idx = blockIdx.x * 256 + threadIdx.x;  // B*T*256 threads, 8 elems each
  int c8 = idx & 255;                        // chunk of 8 within the 2048 K cols
  long row = idx >> 8;
  int t = (int)(row & (T_SEQ - 1));
  int i4 = c8 & 15;                          // chunk within the 128-wide head
  long off = row * QK_STR + 2048 + (long)c8 * 8;
  u16x8 v = *(u16x8*)(X + off);
  float o[8];
#pragma unroll
  for (int j = 0; j < 4; j++) {
    int i = i4 * 4 + j;                      // pair index 0..63
    float inv = __builtin_amdgcn_exp2f((float)i * ROPE_EXP_C);
    float ang = (float)t * inv;
    float cs = __cosf(ang), sn = __sinf(ang);
    float x0 = b2f(v[2 * j]), x1 = b2f(v[2 * j + 1]);
    o[2 * j]     = x0 * cs - x1 * sn;
    o[2 * j + 1] = x1 * cs + x0 * sn;
  }
  u16x8 r;
#pragma unroll
  for (int j = 0; j < 8; j++) r[j] = f2b(o[j]);
  *(u16x8*)(X + off) = r;
}

// ---------------- GEMM: C[M][N] = A[M][K] * Bt[N][K]^T (bf16 in, f32 acc) ----------------
// 256x256 8-phase template, BK=64, 512 thr = 8 waves (2M x 4N), per-wave 128x64 out.
// VWRITE=1 (QKV): V-column blocks (col0>=4096) write plain-layout Vt directly via
// per-wave LDS scratch transpose (measured FREE vs strided C-writes, r16).
#define LOAD_A(q)                                                      \
  _Pragma("unroll") for (int k = 0; k < 2; k++)                        \
  _Pragma("unroll") for (int m = 0; m < 2; m++) {                      \
    int r = wr * 128 + (q) * 32 + m * 16 + lr;                         \
    int cc = (k * 4 + lc) ^ (r & 7);                                   \
    a[k][m] = *(const bf16x8*)&sAb[par * 16384 + r * 64 + cc * 8];     \
  }

#define LOAD_B()                                                       \
  _Pragma("unroll") for (int k = 0; k < 2; k++)                        \
  _Pragma("unroll") for (int n = 0; n < 4; n++) {                      \
    int r = wc * 64 + n * 16 + lr;                                     \
    int cc = (k * 4 + lc) ^ (r & 7);                                   \
    b[k][n] = *(const bf16x8*)&sBb[par * 16384 + r * 64 + cc * 8];     \
  }

#define MFMA_QUAD(q)                                                   \
  _Pragma("unroll") for (int k = 0; k < 2; k++)                        \
  _Pragma("unroll") for (int n = 0; n < 4; n++)                        \
  _Pragma("unroll") for (int m = 0; m < 2; m++)                        \
    acc[(q) * 2 + m][n] = __builtin_amdgcn_mfma_f32_16x16x32_bf16(     \
        a[k][m], b[k][n], acc[(q) * 2 + m][n], 0, 0, 0);

#define STAGE_HALF(g, ld, ldsp, rc0, t_, h_)                           \
  _Pragma("unroll") for (int j = 0; j < 2; j++) {                      \
    int rl = (h_) * 128 + wid * 16 + j * 8 + (lane >> 3);              \
    int cc = (lane & 7) ^ (lane >> 3);                                 \
    GLOAD((g) + ((rc0) + rl) * (long)(ld) + (long)(t_) * 64 + cc * 8,  \
          (ldsp) + (h_) * 128 * 64 + (wid * 16 + j * 8) * 64);         \
  }

template <int OUT_F32, int VWRITE>
__global__ __launch_bounds__(512, 2) void gemm_bt(const u16* __restrict__ A, long lda,
                                                  const u16* __restrict__ Bt,
                                                  void* __restrict__ Cv, long ldc,
                                                  u16* __restrict__ VtOut,
                                                  int M, int N, int K) {
  __shared__ u16 smem[65536];               // sA dbuf (32K u16) | sB dbuf (32K u16)
  u16* sAb = smem;
  u16* sBb = smem + 32768;
  const int tid = threadIdx.x, lane = tid & 63, wid = tid >> 6;
  const int wr = wid >> 2, wc = wid & 3;
  const int lr = lane & 15, lc = lane >> 4;
  const int id = blockIdx.x;
  const int per = (N >> 8) >> 3;             // col-tiles per XCD (1 for N=2048, 3 for 6144)
  const int g8 = id >> 3;
  const long col0 = (long)((id & 7) + 8 * (g8 % per)) * 256;
  const long row0 = (long)(g8 / per) * 256;
  const int NT = K >> 6;                     // NT must be even (K%128==0) for unroll 2

  f32x4 acc[8][4] = {};
  bf16x8 a[2][2], b[2][4];

  STAGE_HALF(Bt, K, sBb, col0, 0, 0);
  STAGE_HALF(Bt, K, sBb, col0, 0, 1);
  STAGE_HALF(A, lda, sAb, row0, 0, 0);
  STAGE_HALF(A, lda, sAb, row0, 0, 1);
  STAGE_HALF(Bt, K, sBb + 16384, col0, 1, 0);
  STAGE_HALF(Bt, K, sBb + 16384, col0, 1, 1);
  VMCNT4();
  BAR();

#pragma unroll 2
  for (int t = 0; t < NT; t++) {
    const int par = t & 1;
    // ---- phase 0 ----
    LOAD_B();
    LOAD_A(0);
    if (t + 1 < NT) { STAGE_HALF(A, lda, sAb + (par ^ 1) * 16384, row0, t + 1, 0); }
    BAR();
    __builtin_amdgcn_s_setprio(1); MFMA_QUAD(0); __builtin_amdgcn_s_setprio(0);
    BAR();
    // ---- phase 1 ----
    LOAD_A(1);
    if (t + 1 < NT) { STAGE_HALF(A, lda, sAb + (par ^ 1) * 16384, row0, t + 1, 1); }
    if (t + 2 < NT) { STAGE_HALF(Bt, K, sBb + par * 16384, col0, t + 2, 0); }
    BAR();
    __builtin_amdgcn_s_setprio(1); MFMA_QUAD(1); __builtin_amdgcn_s_setprio(0);
    BAR();
    // ---- phase 2 ----
    LOAD_A(2);
    if (t + 2 < NT) { STAGE_HALF(Bt, K, sBb + par * 16384, col0, t + 2, 1); }
    BAR();
    __builtin_amdgcn_s_setprio(1); MFMA_QUAD(2); __builtin_amdgcn_s_setprio(0);
    BAR();
    // ---- phase 3 ----
    LOAD_A(3);
    VMCNT4();
    BAR();
    __builtin_amdgcn_s_setprio(1); MFMA_QUAD(3); __builtin_amdgcn_s_setprio(0);
    BAR();
  }

  if (VWRITE && col0 >= 4096) {
    // transpose 128x64 wave-tile through private LDS scratch; store plain Vt rows.
    u16* scr = smem + wid * 8192;            // 16KB per wave, whole 128KB used
#pragma unroll
    for (int mf = 0; mf < 8; mf++)
#pragma unroll
      for (int n = 0; n < 4; n++)
#pragma unroll
        for (int i = 0; i < 4; i++) {
          int sl = mf * 16 + lc * 4 + i;     // s-local 0..127
          int fr = n * 16 + lr;              // f-local 0..63
          scr[fr * 128 + (((sl >> 3) ^ (fr & 7)) << 3) + (sl & 7)] = f2b(acc[mf][n][i]);
        }
    asm volatile("s_waitcnt lgkmcnt(0)" ::: "memory");  // wave-local: own writes done
    const int h0 = (int)((col0 - 4096) >> 7) + (wc >> 1);
    const int f00 = (wc & 1) * 64;
    const long rowbase = row0 + wr * 128;
    const int bb = (int)(rowbase >> 11);
    const int s0 = (int)(rowbase & 2047);
#pragma unroll
    for (int c = 0; c < 16; c++) {
      int fr = c * 4 + (lane >> 4);
      int pc = (lane & 15) ^ (fr & 7);
      u16x8 vv = *(u16x8*)&scr[fr * 128 + pc * 8];
      *(u16x8*)(VtOut + ((long)((bb * 16 + h0) * 128 + f00 + fr)) * 2048 +
                s0 + (lane & 15) * 8) = vv;
    }
  } else {
#pragma unroll
    for (int mf = 0; mf < 8; mf++)
#pragma unroll
      for (int n = 0; n < 4; n++)
#pragma unroll
        for (int i = 0; i < 4; i++) {
          long row = row0 + wr * 128 + mf * 16 + lc * 4 + i;
          long col = col0 + wc * 64 + n * 16 + lr;
          float v = acc[mf][n][i];
          if (OUT_F32) ((float*)Cv)[row * ldc + col] = v;
          else ((u16*)Cv)[row * ldc + col] = f2b(v);
        }
  }
}

// ---------------- flash attention: swapped QK^T, 32x32 MFMA, P in-register ----------------
// r11/r12-proven schedule: K+V double-buffered in LDS, early prefetch, ONE
// __syncthreads per iter. QBLK=128, 4 waves (r17's 8-wave geometry was null).
__global__ __launch_bounds__(256, 2) void attn_kernel(const u16* __restrict__ QK,
                                                      const u16* __restrict__ Vt,
                                                      u16* __restrict__ Y) {
  __shared__ u16 lK[2][64 * 128];   // K tile: 64 s-rows x 128 d (chunk-swizzled)
  __shared__ u16 lV[2][128 * 64];   // Vt tile: 128 d-rows x 64 s (chunk-swizzled)
  const int tid = threadIdx.x, lane = tid & 63, w = tid >> 6;
  const int hi = lane >> 5, l31 = lane & 31;
  const int id = blockIdx.x;
  const int qt = 15 - (id >> 6);    // longest blocks dispatched first
  const int bh = id & 63;
  const int b = bh >> 4, h = bh & 15;
  const int qg = qt * 128 + w * 32 + l31;   // this lane's q row (global)
  const int swz = l31 & 7;

  // Q fragments (B-operand): qf[kd][j] = rope(Q[qg])[kd*16 + hi*8 + j] * scale
  bf16x8 qf[8];
  const long qrow = (long)(b * T_SEQ + qg) * QK_STR + h * DHEAD;
#pragma unroll
  for (int kd = 0; kd < 8; kd++) {
    u16x8 raw = *(const u16x8*)(QK + qrow + kd * 16 + hi * 8);
    bf16x8 q;
#pragma unroll
    for (int jj = 0; jj < 4; jj++) {
      int pi = kd * 8 + hi * 4 + jj;          // pair index 0..63
      float ang = (float)qg * __builtin_amdgcn_exp2f((float)pi * ROPE_EXP_C);
      float cs = __cosf(ang), sn = __sinf(ang);
      float x0 = b2f(raw[2 * jj]), x1 = b2f(raw[2 * jj + 1]);
      q[2 * jj]     = (__bf16)((x0 * cs - x1 * sn) * QSCALE_LOG2E);
      q[2 * jj + 1] = (__bf16)((x1 * cs + x0 * sn) * QSCALE_LOG2E);
    }
    qf[kd] = q;
  }

  f32x16 o0 = {}, o1 = {}, o2 = {}, o3 = {};  // O^T[d][q]: q lane-local
  float m_st = -INFINITY, l_st = 0.f;
  const int nt = (qt + 1) * 2;

#define STAGE(nb, kt_)                                                              \
  {                                                                                 \
    _Pragma("unroll")                                                               \
    for (int j = 0; j < 4; j++) {                                                   \
      int sb = (w * 4 + j) * 64;                                                    \
      int slot = sb + lane;                                                         \
      { int r = slot >> 4, pc = slot & 15, cc = pc ^ (r & 7);                       \
        GLOAD(QK + (long)(b * T_SEQ + (kt_) * 64 + r) * QK_STR + 2048 +             \
                  h * DHEAD + cc * 8,                                               \
              &lK[nb][sb * 8]); }                                                   \
      { int r = slot >> 3, pc = slot & 7, cc = pc ^ (r & 7);                        \
        GLOAD(Vt + (long)(bh * DHEAD + r) * T_SEQ + (kt_) * 64 + cc * 8,            \
              &lV[nb][sb * 8]); }                                                   \
    }                                                                               \
  }

  STAGE(0, 0);
  __syncthreads();

  for (int kt = 0; kt < nt; kt++) {
    const int cur = kt & 1;
    if (kt + 1 < nt) STAGE(cur ^ 1, kt + 1);

    // S^T = mfma(K, Q): st0 = s 0..31, st1 = s 32..63; lane: q=l31, s=crow(r,hi)
    f32x16 st0 = {}, st1 = {};
    __builtin_amdgcn_s_setprio(1);
#pragma unroll
    for (int kd = 0; kd < 8; kd++) {
      int pc = (kd * 2 + hi) ^ swz;
      bf16x8 kf0 = *(const bf16x8*)&lK[cur][l31 * 128 + pc * 8];
      bf16x8 kf1 = *(const bf16x8*)&lK[cur][(32 + l31) * 128 + pc * 8];
      st0 = MFMA32(kf0, qf[kd], st0);
      st1 = MFMA32(kf1, qf[kd], st1);
    }
    __builtin_amdgcn_s_setprio(0);

    // causal mask (diagonal region only)
    if (kt * 64 + 63 > qt * 128 + w * 32) {
#pragma unroll
      for (int r = 0; r < 16; r++) {
        int sl = kt * 64 + (r & 3) + 8 * (r >> 2) + 4 * hi;
        if (sl > qg) st0[r] = -1e30f;
        if (sl + 32 > qg) st1[r] = -1e30f;
      }
    }

    // online softmax, exp2 domain, in-lane + one cross-half shfl reduce
    float mx = -1e30f;
#pragma unroll
    for (int r = 0; r < 16; r++) mx = fmaxf(mx, fmaxf(st0[r], st1[r]));
    mx = fmaxf(mx, __shfl_xor(mx, 32, 64));
    if (__any(mx > m_st + 8.0f)) {     // defer-max
      float mnew = fmaxf(m_st, mx);
      float corr = __builtin_amdgcn_exp2f(m_st - mnew);
      m_st = mnew;
      l_st *= corr;
#pragma unroll
      for (int r = 0; r < 16; r++) {
        o0[r] *= corr; o1[r] *= corr; o2[r] *= corr; o3[r] *= corr;
      }
    }
    float rs = 0.f;
#pragma unroll
    for (int r = 0; r < 16; r++) {
      st0[r] = __builtin_amdgcn_exp2f(st0[r] - m_st); rs += st0[r];
      st1[r] = __builtin_amdgcn_exp2f(st1[r] - m_st); rs += st1[r];
    }
    l_st += rs + __shfl_xor(rs, 32, 64);

    // P -> bf16 PV B-frags: 2 shfls/group (send hi?A:B); O^T += mfma(Vt, P)
    __builtin_amdgcn_s_setprio(1);
#define PVHALF(stX, sb)                                                        \
    _Pragma("unroll")                                                          \
    for (int g = 0; g < 2; g++) {                                              \
      unsigned A0 = pk2(stX[8 * g + 0], stX[8 * g + 1]);                       \
      unsigned A1 = pk2(stX[8 * g + 2], stX[8 * g + 3]);                       \
      unsigned B0 = pk2(stX[8 * g + 4], stX[8 * g + 5]);                       \
      unsigned B1 = pk2(stX[8 * g + 6], stX[8 * g + 7]);                       \
      unsigned r0 = __shfl_xor(hi ? A0 : B0, 32, 64);                          \
      unsigned r1 = __shfl_xor(hi ? A1 : B1, 32, 64);                          \
      u32x4 pw;                                                                \
      pw[0] = hi ? r0 : A0;                                                    \
      pw[1] = hi ? r1 : A1;                                                    \
      pw[2] = hi ? B0 : r0;                                                    \
      pw[3] = hi ? B1 : r1;                                                    \
      bf16x8 pa = *(bf16x8*)&pw;                                               \
      const int ks = (sb) * 2 + g;                                             \
      int pc0 = (ks * 2 + hi) ^ swz;                                           \
      bf16x8 vb0 = *(const bf16x8*)&lV[cur][(l31) * 64 + pc0 * 8];             \
      o0 = MFMA32(vb0, pa, o0);                                                \
      bf16x8 vb1 = *(const bf16x8*)&lV[cur][(32 + l31) * 64 + pc0 * 8];        \
      o1 = MFMA32(vb1, pa, o1);                                                \
      bf16x8 vb2 = *(const bf16x8*)&lV[cur][(64 + l31) * 64 + pc0 * 8];        \
      o2 = MFMA32(vb2, pa, o2);                                                \
      bf16x8 vb3 = *(const bf16x8*)&lV[cur][(96 + l31) * 64 + pc0 * 8];        \
      o3 = MFMA32(vb3, pa, o3);                                                \
    }
    PVHALF(st0, 0)
    PVHALF(st1, 1)
#undef PVHALF
    __builtin_amdgcn_s_setprio(0);

    __syncthreads();
  }

  // epilogue: O^T *= 1/l, packed 8B stores into Y [8192][2048]
  float inv = __builtin_amdgcn_rcpf(l_st);
  const long yrow = (long)(b * T_SEQ + qg) * 2048 + h * DHEAD;
#define WR(oN, n)                                                              \
  _Pragma("unroll")                                                            \
  for (int rq = 0; rq < 4; rq++) {                                             \
    u16x4 pk;                                                                  \
    _Pragma("unroll")                                                          \
    for (int j = 0; j < 4; j++) pk[j] = f2b(oN[rq * 4 + j] * inv);             \
    *(u16x4*)(Y + yrow + (n) * 32 + rq * 8 + hi * 4) = pk;                     \
  }
  WR(o0, 0) WR(o1, 1) WR(o2, 2) WR(o3, 3)
#undef WR
#undef STAGE
}

extern "C" void kernel_launch(void* const* d_in, const int* in_sizes, int n_in,
                              void* d_out, int out_size, void* d_ws, size_t ws_size,
                              hipStream_t stream) {
  const float* x  = (const float*)d_in[0];
  const float* Wq = (const float*)d_in[1];
  const float* Wk = (const float*)d_in[2];
  const float* Wv = (const float*)d_in[3];
  const float* Wo = (const float*)d_in[4];
  float* out = (float*)d_out;
  char* ws = (char*)d_ws;

  const long MB = 1048576L;
  // layout (160MB total): xb 0-32MB (input bf16; becomes Y after attn);
  // Wt4 32-64MB (Wqt|Wkt|Wvt|Wot); Cqk 64-128MB ([8192][4096]: Q-raw | K-roped);
  // Vt 128-160MB ([64*128][2048] plain).
  u16* xb  = (u16*)(ws);
  u16* Wt4 = (u16*)(ws + 32 * MB);
  u16* Cqk = (u16*)(ws + 64 * MB);
  u16* Vtb = (u16*)(ws + 128 * MB);
  u16* Yb  = xb;    // alias: xb dead after QKV projection

  cast_f32_bf16<<<8192, 256, 0, stream>>>(x, xb);
  dim3 wt_g(32, 32, 4);
  wtrans4_kernel<<<wt_g, 256, 0, stream>>>(Wq, Wk, Wv, Wo, Wt4);

  // fused QKV projection: QK cols -> Cqk (ldc 4096); V cols -> Vt directly (transposed)
  gemm_bt<0, 1><<<768, 512, 0, stream>>>(xb, 2048, Wt4, Cqk, 4096, Vtb,
                                         8192, 6144, 2048);

  // standalone K-rope (memory-bound, ~10us); Q roped in attn at load
  rope_k_kernel<<<8192, 256, 0, stream>>>(Cqk);

  attn_kernel<<<1024, 256, 0, stream>>>(Cqk, Vtb, Yb);

  // output projection: A = Y (contiguous stride 2048); Wot at Wt4 + 3*4M elems
  gemm_bt<1, 0><<<256, 512, 0, stream>>>(Yb, 2048, Wt4 + 3 * 4194304L,
                                         (void*)out, 2048, nullptr,
                                         8192, 2048, 2048);
}

// Round 19
// 402.447 us; speedup vs baseline: 1.0280x; 1.0266x over previous
//
#include <hip/hip_runtime.h>
#include <hip/hip_bf16.h>
#include <math.h>

typedef unsigned short u16;
typedef __attribute__((ext_vector_type(8))) __bf16 bf16x8;
typedef __attribute__((ext_vector_type(4))) float f32x4;
typedef __attribute__((ext_vector_type(16))) float f32x16;
typedef __attribute__((ext_vector_type(8))) u16 u16x8;
typedef __attribute__((ext_vector_type(4))) u16 u16x4;
typedef __attribute__((ext_vector_type(4))) unsigned u32x4;

#define T_SEQ 2048
#define DMODEL 2048
#define NH 16
#define DHEAD 128
#define BATCH 4
#define QK_STR 4096             // Cqk row stride (Q | K)
#define ATTN_SCALE 0.08838834764831845f
#define QSCALE_LOG2E 0.1275411278534803f   // ATTN_SCALE * log2(e)
#define ROPE_EXP_C  -0.20762050593045857f  // -log2(10000)/64

#define GLOAD(gp, lp) __builtin_amdgcn_global_load_lds( \
    (const __attribute__((address_space(1))) void*)(gp), \
    (__attribute__((address_space(3))) void*)(lp), 16, 0, 0)

#define BAR() __builtin_amdgcn_s_barrier()
#define VMCNT4() asm volatile("s_waitcnt vmcnt(4)" ::: "memory")
#define MFMA32(A, B, C) __builtin_amdgcn_mfma_f32_32x32x16_bf16(A, B, C, 0, 0, 0)

__device__ __forceinline__ float b2f(u16 u) {
  union { float f; unsigned int i; } x; x.i = ((unsigned int)u) << 16; return x.f;
}
__device__ __forceinline__ u16 f2b(float f) {
  __bf16 h = (__bf16)f;
  return *(u16*)&h;
}
__device__ __forceinline__ unsigned pk2(float lo, float hi2) {
  __bf16 a = (__bf16)lo, b = (__bf16)hi2;
  unsigned short ua = *(unsigned short*)&a, ub = *(unsigned short*)&b;
  return (unsigned)ua | ((unsigned)ub << 16);
}

// ---------------- fused prep: x cast (blocks 0..8191) + 4 weight transposes ----------------
// Branch is block-uniform; wtrans path uses the 16.6KB LDS tile, cast path ignores it
// (cast is BW-bound and saturates at the resulting ~9 blocks/CU occupancy).
__global__ __launch_bounds__(256) void prep_kernel(const float* __restrict__ x,
                                                   const float* __restrict__ W0,
                                                   const float* __restrict__ W1,
                                                   const float* __restrict__ W2,
                                                   const float* __restrict__ W3,
                                                   u16* __restrict__ xb,
                                                   u16* __restrict__ WtBase) {
  __shared__ float tile[64][65];
  const int id = blockIdx.x;
  if (id < 8192) {
    long i = ((long)id * 256 + threadIdx.x) * 8;
    float4 a = *(const float4*)(x + i);
    float4 b = *(const float4*)(x + i + 4);
    u16x8 r;
    r[0] = f2b(a.x); r[1] = f2b(a.y); r[2] = f2b(a.z); r[3] = f2b(a.w);
    r[4] = f2b(b.x); r[5] = f2b(b.y); r[6] = f2b(b.z); r[7] = f2b(b.w);
    *(u16x8*)(xb + i) = r;
    return;
  }
  const int t = id - 8192;
  const int z = t >> 10;                  // weight index 0..3
  const int t10 = t & 1023;
  const int k0 = (t10 >> 5) * 64, n0 = (t10 & 31) * 64;
  const float* W = (z == 0) ? W0 : (z == 1) ? W1 : (z == 2) ? W2 : W3;
  u16* Wt = WtBase + (long)z * 4194304;   // 2048*2048 elements per weight
  const int c = threadIdx.x & 63, r4 = threadIdx.x >> 6;
#pragma unroll
  for (int p = 0; p < 16; p++) {
    int r = p * 4 + r4;
    tile[r][c] = W[(long)(k0 + r) * DMODEL + n0 + c];
  }
  __syncthreads();
#pragma unroll
  for (int p = 0; p < 16; p++) {
    int r = p * 4 + r4;
    Wt[(long)(n0 + r) * DMODEL + k0 + c] = f2b(tile[c][r]);
  }
}

// ---------------- standalone RoPE on the K region only (Cqk cols 2048..4095) ----------------
__global__ __launch_bounds__(256) void rope_k_kernel(u16* __restrict__ X) {
  int idx = blockIdx.x * 256 + threadIdx.x;  // B*T*256 threads, 8 elems each
  int c8 = idx & 255;                        // chunk of 8 within the 2048 K cols
  long row = idx >> 8;
  int t = (int)(row & (T_SEQ - 1));
  int i4 = c8 & 15;                          // chunk within the 128-wide head
  long off = row * QK_STR + 2048 + (long)c8 * 8;
  u16x8 v = *(u16x8*)(X + off);
  float o[8];
#pragma unroll
  for (int j = 0; j < 4; j++) {
    int i = i4 * 4 + j;                      // pair index 0..63
    float inv = __builtin_amdgcn_exp2f((float)i * ROPE_EXP_C);
    float ang = (float)t * inv;
    float cs = __cosf(ang), sn = __sinf(ang);
    float x0 = b2f(v[2 * j]), x1 = b2f(v[2 * j + 1]);
    o[2 * j]     = x0 * cs - x1 * sn;
    o[2 * j + 1] = x1 * cs + x0 * sn;
  }
  u16x8 r;
#pragma unroll
  for (int j = 0; j < 8; j++) r[j] = f2b(o[j]);
  *(u16x8*)(X + off) = r;
}

// ---------------- GEMM: C[M][N] = A[M][K] * Bt[N][K]^T (bf16 in, f32 acc) ----------------
// 256x256 8-phase template, BK=64, 512 thr = 8 waves (2M x 4N), per-wave 128x64 out.
// VWRITE=1 (QKV): V-column blocks (col0>=4096) write plain-layout Vt directly via
// per-wave LDS scratch transpose (measured FREE vs strided C-writes, r16).
#define LOAD_A(q)                                                      \
  _Pragma("unroll") for (int k = 0; k < 2; k++)                        \
  _Pragma("unroll") for (int m = 0; m < 2; m++) {                      \
    int r = wr * 128 + (q) * 32 + m * 16 + lr;                         \
    int cc = (k * 4 + lc) ^ (r & 7);                                   \
    a[k][m] = *(const bf16x8*)&sAb[par * 16384 + r * 64 + cc * 8];     \
  }

#define LOAD_B()                                                       \
  _Pragma("unroll") for (int k = 0; k < 2; k++)                        \
  _Pragma("unroll") for (int n = 0; n < 4; n++) {                      \
    int r = wc * 64 + n * 16 + lr;                                     \
    int cc = (k * 4 + lc) ^ (r & 7);                                   \
    b[k][n] = *(const bf16x8*)&sBb[par * 16384 + r * 64 + cc * 8];     \
  }

#define MFMA_QUAD(q)                                                   \
  _Pragma("unroll") for (int k = 0; k < 2; k++)                        \
  _Pragma("unroll") for (int n = 0; n < 4; n++)                        \
  _Pragma("unroll") for (int m = 0; m < 2; m++)                        \
    acc[(q) * 2 + m][n] = __builtin_amdgcn_mfma_f32_16x16x32_bf16(     \
        a[k][m], b[k][n], acc[(q) * 2 + m][n], 0, 0, 0);

#define STAGE_HALF(g, ld, ldsp, rc0, t_, h_)                           \
  _Pragma("unroll") for (int j = 0; j < 2; j++) {                      \
    int rl = (h_) * 128 + wid * 16 + j * 8 + (lane >> 3);              \
    int cc = (lane & 7) ^ (lane >> 3);                                 \
    GLOAD((g) + ((rc0) + rl) * (long)(ld) + (long)(t_) * 64 + cc * 8,  \
          (ldsp) + (h_) * 128 * 64 + (wid * 16 + j * 8) * 64);         \
  }

template <int OUT_F32, int VWRITE>
__global__ __launch_bounds__(512, 2) void gemm_bt(const u16* __restrict__ A, long lda,
                                                  const u16* __restrict__ Bt,
                                                  void* __restrict__ Cv, long ldc,
                                                  u16* __restrict__ VtOut,
                                                  int M, int N, int K) {
  __shared__ u16 smem[65536];               // sA dbuf (32K u16) | sB dbuf (32K u16)
  u16* sAb = smem;
  u16* sBb = smem + 32768;
  const int tid = threadIdx.x, lane = tid & 63, wid = tid >> 6;
  const int wr = wid >> 2, wc = wid & 3;
  const int lr = lane & 15, lc = lane >> 4;
  const int id = blockIdx.x;
  const int per = (N >> 8) >> 3;             // col-tiles per XCD (1 for N=2048, 3 for 6144)
  const int g8 = id >> 3;
  const long col0 = (long)((id & 7) + 8 * (g8 % per)) * 256;
  const long row0 = (long)(g8 / per) * 256;
  const int NT = K >> 6;                     // NT must be even (K%128==0) for unroll 2

  f32x4 acc[8][4] = {};
  bf16x8 a[2][2], b[2][4];

  STAGE_HALF(Bt, K, sBb, col0, 0, 0);
  STAGE_HALF(Bt, K, sBb, col0, 0, 1);
  STAGE_HALF(A, lda, sAb, row0, 0, 0);
  STAGE_HALF(A, lda, sAb, row0, 0, 1);
  STAGE_HALF(Bt, K, sBb + 16384, col0, 1, 0);
  STAGE_HALF(Bt, K, sBb + 16384, col0, 1, 1);
  VMCNT4();
  BAR();

#pragma unroll 2
  for (int t = 0; t < NT; t++) {
    const int par = t & 1;
    // ---- phase 0 ----
    LOAD_B();
    LOAD_A(0);
    if (t + 1 < NT) { STAGE_HALF(A, lda, sAb + (par ^ 1) * 16384, row0, t + 1, 0); }
    BAR();
    __builtin_amdgcn_s_setprio(1); MFMA_QUAD(0); __builtin_amdgcn_s_setprio(0);
    BAR();
    // ---- phase 1 ----
    LOAD_A(1);
    if (t + 1 < NT) { STAGE_HALF(A, lda, sAb + (par ^ 1) * 16384, row0, t + 1, 1); }
    if (t + 2 < NT) { STAGE_HALF(Bt, K, sBb + par * 16384, col0, t + 2, 0); }
    BAR();
    __builtin_amdgcn_s_setprio(1); MFMA_QUAD(1); __builtin_amdgcn_s_setprio(0);
    BAR();
    // ---- phase 2 ----
    LOAD_A(2);
    if (t + 2 < NT) { STAGE_HALF(Bt, K, sBb + par * 16384, col0, t + 2, 1); }
    BAR();
    __builtin_amdgcn_s_setprio(1); MFMA_QUAD(2); __builtin_amdgcn_s_setprio(0);
    BAR();
    // ---- phase 3 ----
    LOAD_A(3);
    VMCNT4();
    BAR();
    __builtin_amdgcn_s_setprio(1); MFMA_QUAD(3); __builtin_amdgcn_s_setprio(0);
    BAR();
  }

  if (VWRITE && col0 >= 4096) {
    // transpose 128x64 wave-tile through private LDS scratch; store plain Vt rows.
    u16* scr = smem + wid * 8192;            // 16KB per wave, whole 128KB used
#pragma unroll
    for (int mf = 0; mf < 8; mf++)
#pragma unroll
      for (int n = 0; n < 4; n++)
#pragma unroll
        for (int i = 0; i < 4; i++) {
          int sl = mf * 16 + lc * 4 + i;     // s-local 0..127
          int fr = n * 16 + lr;              // f-local 0..63
          scr[fr * 128 + (((sl >> 3) ^ (fr & 7)) << 3) + (sl & 7)] = f2b(acc[mf][n][i]);
        }
    asm volatile("s_waitcnt lgkmcnt(0)" ::: "memory");  // wave-local: own writes done
    const int h0 = (int)((col0 - 4096) >> 7) + (wc >> 1);
    const int f00 = (wc & 1) * 64;
    const long rowbase = row0 + wr * 128;
    const int bb = (int)(rowbase >> 11);
    const int s0 = (int)(rowbase & 2047);
#pragma unroll
    for (int c = 0; c < 16; c++) {
      int fr = c * 4 + (lane >> 4);
      int pc = (lane & 15) ^ (fr & 7);
      u16x8 vv = *(u16x8*)&scr[fr * 128 + pc * 8];
      *(u16x8*)(VtOut + ((long)((bb * 16 + h0) * 128 + f00 + fr)) * 2048 +
                s0 + (lane & 15) * 8) = vv;
    }
  } else {
#pragma unroll
    for (int mf = 0; mf < 8; mf++)
#pragma unroll
      for (int n = 0; n < 4; n++)
#pragma unroll
        for (int i = 0; i < 4; i++) {
          long row = row0 + wr * 128 + mf * 16 + lc * 4 + i;
          long col = col0 + wc * 64 + n * 16 + lr;
          float v = acc[mf][n][i];
          if (OUT_F32) ((float*)Cv)[row * ldc + col] = v;
          else ((u16*)Cv)[row * ldc + col] = f2b(v);
        }
  }
}

// ---------------- flash attention: swapped QK^T, 32x32 MFMA, P in-register ----------------
// r11/r12-proven schedule: K+V double-buffered in LDS, early prefetch, ONE
// __syncthreads per iter. QBLK=128, 4 waves.
__global__ __launch_bounds__(256, 2) void attn_kernel(const u16* __restrict__ QK,
                                                      const u16* __restrict__ Vt,
                                                      u16* __restrict__ Y) {
  __shared__ u16 lK[2][64 * 128];   // K tile: 64 s-rows x 128 d (chunk-swizzled)
  __shared__ u16 lV[2][128 * 64];   // Vt tile: 128 d-rows x 64 s (chunk-swizzled)
  const int tid = threadIdx.x, lane = tid & 63, w = tid >> 6;
  const int hi = lane >> 5, l31 = lane & 31;
  const int id = blockIdx.x;
  const int qt = 15 - (id >> 6);    // longest blocks dispatched first
  const int bh = id & 63;
  const int b = bh >> 4, h = bh & 15;
  const int qg = qt * 128 + w * 32 + l31;   // this lane's q row (global)
  const int swz = l31 & 7;

  // Q fragments (B-operand): qf[kd][j] = rope(Q[qg])[kd*16 + hi*8 + j] * scale
  bf16x8 qf[8];
  const long qrow = (long)(b * T_SEQ + qg) * QK_STR + h * DHEAD;
#pragma unroll
  for (int kd = 0; kd < 8; kd++) {
    u16x8 raw = *(const u16x8*)(QK + qrow + kd * 16 + hi * 8);
    bf16x8 q;
#pragma unroll
    for (int jj = 0; jj < 4; jj++) {
      int pi = kd * 8 + hi * 4 + jj;          // pair index 0..63
      float ang = (float)qg * __builtin_amdgcn_exp2f((float)pi * ROPE_EXP_C);
      float cs = __cosf(ang), sn = __sinf(ang);
      float x0 = b2f(raw[2 * jj]), x1 = b2f(raw[2 * jj + 1]);
      q[2 * jj]     = (__bf16)((x0 * cs - x1 * sn) * QSCALE_LOG2E);
      q[2 * jj + 1] = (__bf16)((x1 * cs + x0 * sn) * QSCALE_LOG2E);
    }
    qf[kd] = q;
  }

  f32x16 o0 = {}, o1 = {}, o2 = {}, o3 = {};  // O^T[d][q]: q lane-local
  float m_st = -INFINITY, l_st = 0.f;
  const int nt = (qt + 1) * 2;

#define STAGE(nb, kt_)                                                              \
  {                                                                                 \
    _Pragma("unroll")                                                               \
    for (int j = 0; j < 4; j++) {                                                   \
      int sb = (w * 4 + j) * 64;                                                    \
      int slot = sb + lane;                                                         \
      { int r = slot >> 4, pc = slot & 15, cc = pc ^ (r & 7);                       \
        GLOAD(QK + (long)(b * T_SEQ + (kt_) * 64 + r) * QK_STR + 2048 +             \
                  h * DHEAD + cc * 8,                                               \
              &lK[nb][sb * 8]); }                                                   \
      { int r = slot >> 3, pc = slot & 7, cc = pc ^ (r & 7);                        \
        GLOAD(Vt + (long)(bh * DHEAD + r) * T_SEQ + (kt_) * 64 + cc * 8,            \
              &lV[nb][sb * 8]); }                                                   \
    }                                                                               \
  }

  STAGE(0, 0);
  __syncthreads();

  for (int kt = 0; kt < nt; kt++) {
    const int cur = kt & 1;
    if (kt + 1 < nt) STAGE(cur ^ 1, kt + 1);

    // S^T = mfma(K, Q): st0 = s 0..31, st1 = s 32..63; lane: q=l31, s=crow(r,hi)
    f32x16 st0 = {}, st1 = {};
    __builtin_amdgcn_s_setprio(1);
#pragma unroll
    for (int kd = 0; kd < 8; kd++) {
      int pc = (kd * 2 + hi) ^ swz;
      bf16x8 kf0 = *(const bf16x8*)&lK[cur][l31 * 128 + pc * 8];
      bf16x8 kf1 = *(const bf16x8*)&lK[cur][(32 + l31) * 128 + pc * 8];
      st0 = MFMA32(kf0, qf[kd], st0);
      st1 = MFMA32(kf1, qf[kd], st1);
    }
    __builtin_amdgcn_s_setprio(0);

    // causal mask (diagonal region only)
    if (kt * 64 + 63 > qt * 128 + w * 32) {
#pragma unroll
      for (int r = 0; r < 16; r++) {
        int sl = kt * 64 + (r & 3) + 8 * (r >> 2) + 4 * hi;
        if (sl > qg) st0[r] = -1e30f;
        if (sl + 32 > qg) st1[r] = -1e30f;
      }
    }

    // online softmax, exp2 domain, in-lane + one cross-half shfl reduce
    float mx = -1e30f;
#pragma unroll
    for (int r = 0; r < 16; r++) mx = fmaxf(mx, fmaxf(st0[r], st1[r]));
    mx = fmaxf(mx, __shfl_xor(mx, 32, 64));
    if (__any(mx > m_st + 8.0f)) {     // defer-max
      float mnew = fmaxf(m_st, mx);
      float corr = __builtin_amdgcn_exp2f(m_st - mnew);
      m_st = mnew;
      l_st *= corr;
#pragma unroll
      for (int r = 0; r < 16; r++) {
        o0[r] *= corr; o1[r] *= corr; o2[r] *= corr; o3[r] *= corr;
      }
    }
    float rs = 0.f;
#pragma unroll
    for (int r = 0; r < 16; r++) {
      st0[r] = __builtin_amdgcn_exp2f(st0[r] - m_st); rs += st0[r];
      st1[r] = __builtin_amdgcn_exp2f(st1[r] - m_st); rs += st1[r];
    }
    l_st += rs + __shfl_xor(rs, 32, 64);

    // P -> bf16 PV B-frags: 2 shfls/group (send hi?A:B); O^T += mfma(Vt, P)
    __builtin_amdgcn_s_setprio(1);
#define PVHALF(stX, sb)                                                        \
    _Pragma("unroll")                                                          \
    for (int g = 0; g < 2; g++) {                                              \
      unsigned A0 = pk2(stX[8 * g + 0], stX[8 * g + 1]);                       \
      unsigned A1 = pk2(stX[8 * g + 2], stX[8 * g + 3]);                       \
      unsigned B0 = pk2(stX[8 * g + 4], stX[8 * g + 5]);                       \
      unsigned B1 = pk2(stX[8 * g + 6], stX[8 * g + 7]);                       \
      unsigned r0 = __shfl_xor(hi ? A0 : B0, 32, 64);                          \
      unsigned r1 = __shfl_xor(hi ? A1 : B1, 32, 64);                          \
      u32x4 pw;                                                                \
      pw[0] = hi ? r0 : A0;                                                    \
      pw[1] = hi ? r1 : A1;                                                    \
      pw[2] = hi ? B0 : r0;                                                    \
      pw[3] = hi ? B1 : r1;                                                    \
      bf16x8 pa = *(bf16x8*)&pw;                                               \
      const int ks = (sb) * 2 + g;                                             \
      int pc0 = (ks * 2 + hi) ^ swz;                                           \
      bf16x8 vb0 = *(const bf16x8*)&lV[cur][(l31) * 64 + pc0 * 8];             \
      o0 = MFMA32(vb0, pa, o0);                                                \
      bf16x8 vb1 = *(const bf16x8*)&lV[cur][(32 + l31) * 64 + pc0 * 8];        \
      o1 = MFMA32(vb1, pa, o1);                                                \
      bf16x8 vb2 = *(const bf16x8*)&lV[cur][(64 + l31) * 64 + pc0 * 8];        \
      o2 = MFMA32(vb2, pa, o2);                                                \
      bf16x8 vb3 = *(const bf16x8*)&lV[cur][(96 + l31) * 64 + pc0 * 8];        \
      o3 = MFMA32(vb3, pa, o3);                                                \
    }
    PVHALF(st0, 0)
    PVHALF(st1, 1)
#undef PVHALF
    __builtin_amdgcn_s_setprio(0);

    __syncthreads();
  }

  // epilogue: O^T *= 1/l, packed 8B stores into Y [8192][2048]
  float inv = __builtin_amdgcn_rcpf(l_st);
  const long yrow = (long)(b * T_SEQ + qg) * 2048 + h * DHEAD;
#define WR(oN, n)                                                              \
  _Pragma("unroll")                                                            \
  for (int rq = 0; rq < 4; rq++) {                                             \
    u16x4 pk;                                                                  \
    _Pragma("unroll")                                                          \
    for (int j = 0; j < 4; j++) pk[j] = f2b(oN[rq * 4 + j] * inv);             \
    *(u16x4*)(Y + yrow + (n) * 32 + rq * 8 + hi * 4) = pk;                     \
  }
  WR(o0, 0) WR(o1, 1) WR(o2, 2) WR(o3, 3)
#undef WR
#undef STAGE
}

extern "C" void kernel_launch(void* const* d_in, const int* in_sizes, int n_in,
                              void* d_out, int out_size, void* d_ws, size_t ws_size,
                              hipStream_t stream) {
  const float* x  = (const float*)d_in[0];
  const float* Wq = (const float*)d_in[1];
  const float* Wk = (const float*)d_in[2];
  const float* Wv = (const float*)d_in[3];
  const float* Wo = (const float*)d_in[4];
  float* out = (float*)d_out;
  char* ws = (char*)d_ws;

  const long MB = 1048576L;
  // layout (160MB total): xb 0-32MB (input bf16; becomes Y after attn);
  // Wt4 32-64MB (Wqt|Wkt|Wvt|Wot); Cqk 64-128MB ([8192][4096]: Q-raw | K-roped);
  // Vt 128-160MB ([64*128][2048] plain).
  u16* xb  = (u16*)(ws);
  u16* Wt4 = (u16*)(ws + 32 * MB);
  u16* Cqk = (u16*)(ws + 64 * MB);
  u16* Vtb = (u16*)(ws + 128 * MB);
  u16* Yb  = xb;    // alias: xb dead after QKV projection

  // fused prep: x cast + 4 weight transposes in one dispatch
  prep_kernel<<<12288, 256, 0, stream>>>(x, Wq, Wk, Wv, Wo, xb, Wt4);

  // fused QKV projection: QK cols -> Cqk (ldc 4096); V cols -> Vt directly (transposed)
  gemm_bt<0, 1><<<768, 512, 0, stream>>>(xb, 2048, Wt4, Cqk, 4096, Vtb,
                                         8192, 6144, 2048);

  // standalone K-rope (memory-bound, ~10us); Q roped in attn at load
  rope_k_kernel<<<8192, 256, 0, stream>>>(Cqk);

  attn_kernel<<<1024, 256, 0, stream>>>(Cqk, Vtb, Yb);

  // output projection: A = Y (contiguous stride 2048); Wot at Wt4 + 3*4M elems
  gemm_bt<1, 0><<<256, 512, 0, stream>>>(Yb, 2048, Wt4 + 3 * 4194304L,
                                         (void*)out, 2048, nullptr,
                                         8192, 2048, 2048);
}